// Round 8
// baseline (222.477 us; speedup 1.0000x reference)
//
#include <hip/hip_runtime.h>
#include <hip/hip_bf16.h>

typedef unsigned short ushort_t;
typedef __attribute__((ext_vector_type(8))) short short8;
typedef __attribute__((ext_vector_type(4))) float floatx4;

#define G_   129
#define F_   96
#define O_   96
#define T_   512
#define KD   288    // K*F, kd = kk*96 + f
#define LDB  296    // Wl padded row stride (288 + 8)
#define SROW 40     // x-slab row stride in ushorts (80 B) -> bank-conflict-free
#define SLAB (36 * SROW)   // per-wave slab: 36 rows (34 used) = 2880 B
#define WCHUNKS 6912       // 96*288/4 dwordx4 chunks of one group's raw weights

// f32 -> bf16 RNE (finite inputs)
__device__ __forceinline__ unsigned f2bf(float f) {
    unsigned u = __builtin_bit_cast(unsigned, f);
    u += 0x7FFFu + ((u >> 16) & 1u);
    return u >> 16;
}
// packed pair f32x2 -> bf16x2 in one dword (integer ops only)
__device__ __forceinline__ unsigned pk2(float a, float b) {
    return f2bf(a) | (f2bf(b) << 16);
}

// Single kernel: in-block weight permute (raw f32 [O,F,K] -> LDS bf16 [O, kk*96+f])
// + per-wave x slab staging + MFMA K-loop. No wt_permute dispatch, no d_ws.
__global__ __launch_bounds__(512, 4) void conv_mfma(
    const float* __restrict__ x, const float* __restrict__ w,
    const float* __restrict__ bias, float* __restrict__ out)
{
    __shared__ __align__(16) ushort_t Wl[O_ * LDB];   // 56,832 B
    __shared__ __align__(16) ushort_t Xs[8 * SLAB];   // 23,040 B

    const int g    = blockIdx.y;
    const int m0   = blockIdx.x * 256;
    const int tid  = threadIdx.x;
    const int wave = tid >> 6;
    const int lane = tid & 63;
    const int ln   = lane & 15;
    const int q    = lane >> 4;

    // ---- x slab task constants (per-wave private slab; rows 0..33 hold t = tb+row-1)
    const int m0r = m0 + wave * 32;
    const int b   = m0r >> 9;
    const int tb  = m0r & 511;

    const float* tp[5];
    int  laddr[5];
    bool wr[5], vld[5];
    #pragma unroll
    for (int i = 0; i < 5; ++i) {
        int task = i * 64 + lane;
        int row = task >> 3;            // 0..39
        int seg = task & 7;             // 8 segs x 4 floats = one 32-f block
        int tl = tb + row - 1;
        wr[i]  = row < 34;
        vld[i] = wr[i] && ((unsigned)tl < (unsigned)T_);
        int tc = tl < 0 ? 0 : (tl > T_ - 1 ? T_ - 1 : tl);
        tp[i] = x + ((size_t)((b * T_ + tc) * G_ + g) * F_ + seg * 4);
        laddr[i] = wave * SLAB + row * SROW + seg * 4;
    }

    auto issueX = [&](int fb, floatx4* v) {
        #pragma unroll
        for (int i = 0; i < 5; ++i)
            v[i] = *(const floatx4*)(tp[i] + fb * 32);
    };
    auto writeX = [&](const floatx4* v) {
        #pragma unroll
        for (int i = 0; i < 5; ++i) {
            if (wr[i]) {
                unsigned lo = pk2(v[i][0], v[i][1]);
                unsigned hi = pk2(v[i][2], v[i][3]);
                if (!vld[i]) { lo = 0u; hi = 0u; }
                uint2 d; d.x = lo; d.y = hi;
                *(uint2*)&Xs[laddr[i]] = d;
            }
        }
    };

    floatx4 cur[5], nxt[5];
    issueX(0, cur);   // x loads in flight while we permute weights

    // ---- in-kernel weight permute+convert.
    // Raw group weights: 27,648 contiguous f32, linear = (o*96+f)*3+kk.
    // 4 | 288 -> each dwordx4 chunk stays within one o-row, rem multiple of 4.
    // Loads: lane-consecutive 16B = fully coalesced. Writes: u16 scatter into
    // Wl[o][kk*96+f] (<=4-way bank aliasing, one-time cost).
    {
        const float* wg = w + (size_t)g * (O_ * KD);
        #pragma unroll
        for (int bb = 0; bb < 2; ++bb) {
            floatx4 wv[7];
            #pragma unroll
            for (int i = 0; i < 7; ++i) {
                int chunk = (bb * 7 + i) * 512 + tid;
                int ch = chunk < WCHUNKS ? chunk : WCHUNKS - 1;
                wv[i] = *(const floatx4*)(wg + (size_t)ch * 4);
            }
            #pragma unroll
            for (int i = 0; i < 7; ++i) {
                int chunk = (bb * 7 + i) * 512 + tid;
                if (chunk < WCHUNKS) {
                    int o   = chunk / 72;            // 72 chunks per o-row
                    int rem = (chunk - o * 72) * 4;  // 0..284, multiple of 4
                    #pragma unroll
                    for (int e = 0; e < 4; ++e) {
                        int re = rem + e;            // < 288, no row wrap
                        int f  = re / 3;
                        int kk = re - f * 3;
                        Wl[o * LDB + kk * 96 + f] = (ushort_t)f2bf(wv[i][e]);
                    }
                }
            }
        }
    }
    __syncthreads();   // the only barrier

    floatx4 acc[2][6];
    #pragma unroll
    for (int s = 0; s < 2; ++s)
        #pragma unroll
        for (int nt = 0; nt < 6; ++nt)
            acc[s][nt] = (floatx4){0.f, 0.f, 0.f, 0.f};

    #pragma unroll
    for (int fb = 0; fb < 3; ++fb) {
        if (fb < 2) issueX(fb + 1, nxt);   // keep next f-block's 5 loads in flight
        writeX(cur);                        // waits only on cur's loads

        #pragma unroll
        for (int kk = 0; kk < 3; ++kk) {
            const short8 a0 = *(const short8*)&Xs[wave * SLAB + (ln + kk) * SROW + q * 8];
            const short8 a1 = *(const short8*)&Xs[wave * SLAB + (16 + ln + kk) * SROW + q * 8];
            const int c32 = (kk * 3 + fb) * 32;   // Wl column block kd = kk*96 + fb*32
            #pragma unroll
            for (int nt = 0; nt < 6; ++nt) {
                const short8 bb = *(const short8*)&Wl[(nt * 16 + ln) * LDB + c32 + q * 8];
                acc[0][nt] = __builtin_amdgcn_mfma_f32_16x16x32_bf16(a0, bb, acc[0][nt], 0, 0, 0);
                acc[1][nt] = __builtin_amdgcn_mfma_f32_16x16x32_bf16(a1, bb, acc[1][nt], 0, 0, 0);
            }
        }
        #pragma unroll
        for (int i = 0; i < 5; ++i) cur[i] = nxt[i];
    }

    // Epilogue: D row = q*4 + reg, col = ln; + bias; f32 out.
    #pragma unroll
    for (int s = 0; s < 2; ++s) {
        int mbase = m0 + wave * 32 + s * 16 + q * 4;
        #pragma unroll
        for (int nt = 0; nt < 6; ++nt) {
            int o = nt * 16 + ln;
            float bv = bias[g * O_ + o];
            #pragma unroll
            for (int r = 0; r < 4; ++r) {
                int m = mbase + r;
                out[(size_t)(m * G_ + g) * O_ + o] = acc[s][nt][r] + bv;
            }
        }
    }
}

extern "C" void kernel_launch(void* const* d_in, const int* in_sizes, int n_in,
                              void* d_out, int out_size, void* d_ws, size_t ws_size,
                              hipStream_t stream) {
    const float* x    = (const float*)d_in[0];
    const float* w    = (const float*)d_in[1];
    const float* bias = (const float*)d_in[2];
    float* out = (float*)d_out;

    dim3 grid(2048 / 256, G_);
    conv_mfma<<<grid, dim3(512), 0, stream>>>(x, w, bias, out);
}